// Round 4
// baseline (138.810 us; speedup 1.0000x reference)
//
#include <hip/hip_runtime.h>
#include <hip/hip_bf16.h>

// Problem constants: B=64, T=N=1024, d=64, k=128.

typedef __attribute__((ext_vector_type(8))) short bfrag;   // 8 x bf16 (4 VGPRs)
typedef __attribute__((ext_vector_type(4))) float ffrag;   // 4 x f32 acc

__device__ __forceinline__ unsigned short f2b(float f) {
  unsigned u = __builtin_bit_cast(unsigned, f);
  u += 0x7FFFu + ((u >> 16) & 1u);          // RNE f32 -> bf16 (finite inputs)
  return (unsigned short)(u >> 16);
}
__device__ __forceinline__ float b2f(unsigned short h) {
  return __builtin_bit_cast(float, (unsigned)h << 16);
}
__device__ __forceinline__ float ftanh(float x) {
  // tanh(x) = 1 - 2/(2^(x*2*log2e)+1); ~1e-6 abs err
  float e = __builtin_amdgcn_exp2f(x * 2.88539008177792681f);
  return fmaf(-2.0f, __builtin_amdgcn_rcpf(e + 1.0f), 1.0f);
}
// pack two f32 -> packed bf16 pair {lo, hi}; round-half-up (+0x8000) then one
// v_perm_b32 takes the two high halves.
__device__ __forceinline__ unsigned pack2(float lo, float hi) {
  unsigned a = __builtin_bit_cast(unsigned, lo) + 0x8000u;
  unsigned b = __builtin_bit_cast(unsigned, hi) + 0x8000u;
  return __builtin_amdgcn_perm(b, a, 0x07060302u);
}

#define MFMA(a, b, c) __builtin_amdgcn_mfma_f32_16x16x32_bf16((a), (b), (c), 0, 0, 0)

// ---------------------------------------------------------------------------
// prep: RWb = bf16(review@Wl)  [B,T,64]
//       Rb  = bf16(Wr@review^T) stored [B,128,T]
//       Pb  = bf16(Wp@post^T)   stored [B,128,N]
//       postb = bf16(post)      [B,N,64]
// ---------------------------------------------------------------------------
__global__ __launch_bounds__(256) void prep_kernel(
    const float* __restrict__ review, const float* __restrict__ post,
    const float* __restrict__ Wl, const float* __restrict__ Wr,
    const float* __restrict__ Wp,
    unsigned short* __restrict__ RWb, unsigned short* __restrict__ Rb,
    unsigned short* __restrict__ Pb, unsigned short* __restrict__ postb)
{
  const int chunk = blockIdx.x, b = blockIdx.y, side = blockIdx.z;
  const int tid = threadIdx.x, lane = tid & 63, w = tid >> 6;
  const int lr = lane & 15, lg = lane >> 4;
  const int r0 = chunk * 128;

  __shared__ __align__(16) unsigned short seqs[128][72];  // seq rows [r][d]
  __shared__ __align__(16) unsigned short wgt[128][72];   // Wr or Wp [k][d]
  __shared__ __align__(16) unsigned short wlt[64][72];    // Wl^T [i][d]

  const float* seq = (side == 0) ? review : post;
  for (int i = tid; i < 128 * 64; i += 256) {
    int r = i >> 6, d = i & 63;
    unsigned short h = f2b(seq[((size_t)(b * 1024 + r0 + r)) * 64 + d]);
    seqs[r][d] = h;
    if (side == 1) postb[((size_t)(b * 1024 + r0 + r)) * 64 + d] = h;
  }
  const float* wkd = (side == 0) ? Wr : Wp;
  for (int i = tid; i < 128 * 64; i += 256) {
    int k = i >> 6, d = i & 63;
    wgt[k][d] = f2b(wkd[k * 64 + d]);
  }
  if (side == 0) {
    for (int i = tid; i < 64 * 64; i += 256) {
      int d = i >> 6, c = i & 63;
      wlt[c][d] = f2b(Wl[d * 64 + c]);
    }
  }
  __syncthreads();

  if (side == 0) {
    // RW = seqs @ Wl : [128 x 64]; wave w owns t in [32w, 32w+32)
    ffrag acc[2][4] = {};
#pragma unroll
    for (int ks = 0; ks < 2; ++ks)
#pragma unroll
      for (int ts = 0; ts < 2; ++ts) {
        bfrag a = *(const bfrag*)&seqs[w * 32 + ts * 16 + lr][ks * 32 + lg * 8];
#pragma unroll
        for (int is = 0; is < 4; ++is) {
          bfrag bb = *(const bfrag*)&wlt[is * 16 + lr][ks * 32 + lg * 8];
          acc[ts][is] = MFMA(a, bb, acc[ts][is]);
        }
      }
#pragma unroll
    for (int ts = 0; ts < 2; ++ts)
#pragma unroll
      for (int is = 0; is < 4; ++is)
#pragma unroll
        for (int j = 0; j < 4; ++j) {
          int t = r0 + w * 32 + ts * 16 + lg * 4 + j;
          int i2 = is * 16 + lr;
          RWb[((size_t)(b * 1024 + t)) * 64 + i2] = f2b(acc[ts][is][j]);
        }
  }
  {
    // R/P = wgt @ seqs^T : [128 k x 128 r]; wave w owns k in [32w, 32w+32)
    ffrag acc[2][8] = {};
#pragma unroll
    for (int ks = 0; ks < 2; ++ks)
#pragma unroll
      for (int ksb = 0; ksb < 2; ++ksb) {
        bfrag a = *(const bfrag*)&wgt[w * 32 + ksb * 16 + lr][ks * 32 + lg * 8];
#pragma unroll
        for (int ts = 0; ts < 8; ++ts) {
          bfrag bb = *(const bfrag*)&seqs[ts * 16 + lr][ks * 32 + lg * 8];
          acc[ksb][ts] = MFMA(a, bb, acc[ksb][ts]);
        }
      }
    unsigned short* dst = (side == 0) ? Rb : Pb;
#pragma unroll
    for (int ksb = 0; ksb < 2; ++ksb)
#pragma unroll
      for (int ts = 0; ts < 8; ++ts)
#pragma unroll
        for (int j = 0; j < 4; ++j) {
          int k = w * 32 + ksb * 16 + lg * 4 + j;
          int t = r0 + ts * 16 + lr;
          dst[((size_t)(b * 128 + k)) * 1024 + t] = f2b(acc[ksb][ts][j]);
        }
  }
}

// ---------------------------------------------------------------------------
// hz (fused hp+hr), v4: direct-to-register A-fragments (no rl/rwl staging),
// double-buffered L tile, ONE barrier per iteration.
// role 0: z_p (resident=post strip, chunk over t, coeff=R, add=P)
// role 1: z_r (resident=RW strip, chunk over n, coeff=P, add=R)
// LDS (32768 B): postl @0 [128 rows][128B] XOR-swizzled resident strip
//                ll0 @16384, ll1 @24576: [4 slots][128 res][16B] frag-major L
// A-frag global pattern: 16 rows x 128B-stride, 4 lanes x 16B per 64B line
// -> 16 lines/instr, fully coalesced, L1/L2-resident.
// ---------------------------------------------------------------------------
__global__ __launch_bounds__(256, 4) void hz_kernel(
    const unsigned short* __restrict__ RWb, const unsigned short* __restrict__ Rb,
    const unsigned short* __restrict__ Pb, const unsigned short* __restrict__ postb,
    const float* __restrict__ whp, const float* __restrict__ whr,
    float* __restrict__ zp, float* __restrict__ zr)
{
  const int orig = blockIdx.x;
  const int swz = (orig & 7) * 128 + (orig >> 3);   // XCD-chunked, bijective
  const int strip = swz & 7, pair = swz >> 3;
  const int b = pair & 63, role = pair >> 6;
  const int s0 = strip * 128;
  const int tid = threadIdx.x, lane = tid & 63, w = tid >> 6;
  const int lr = lane & 15, lg = lane >> 4;

  const unsigned short* resident = role ? RWb : postb;
  const unsigned short* chunkseq = role ? postb : RWb;
  const unsigned short* coeff    = role ? Pb : Rb;
  const unsigned short* addterm  = role ? Rb : Pb;
  const float* wh                = role ? whr : whp;
  float* zout                    = role ? zr : zp;

  __shared__ __align__(16) char smem[32768];
  char* postl = smem;                    // swizzled rows of 128B
  char* ll0   = smem + 16384;            // [slot][res][16B]
  char* ll1   = smem + 24576;
  float* zacc = (float*)(smem + 16384);  // alias ll0 (epilogue only)

  // per-lane global fragment bases
  const char* cbase = (const char*)chunkseq + (size_t)b * 131072
                      + (size_t)lr * 128 + lg * 16;          // + tc*4096 + ts*2048 + ks*64
  const char* kbase = (const char*)coeff + (size_t)b * 262144
                      + (size_t)(w * 32 + lr) * 2048 + lg * 16;  // + tc*64 + ksb*32768

  // ---- prologue: A-frags for chunk 0 ----
  bfrag cfU[4], kfU[2];
#pragma unroll
  for (int ts = 0; ts < 2; ++ts)
#pragma unroll
    for (int ks = 0; ks < 2; ++ks)
      cfU[ts * 2 + ks] = *(const bfrag*)(cbase + ts * 2048 + ks * 64);
  kfU[0] = *(const bfrag*)(kbase);
  kfU[1] = *(const bfrag*)(kbase + 32768);

  // ---- prologue: resident strip (swizzled rows) ----
  {
    const char* src = (const char*)resident + ((size_t)(b * 1024 + s0)) * 128;
    const int row = tid >> 1, half = tid & 1;
#pragma unroll
    for (int q = 0; q < 4; ++q) {
      int slot = half * 4 + q;
      uint4 v = *(const uint4*)(src + row * 128 + slot * 16);
      *(uint4*)(postl + row * 128 + ((slot ^ (row & 7)) << 4)) = v;
    }
  }
  __syncthreads();   // postl ready

  // ---- prologue: L(0) -> ll0 ----
  {
    bfrag bb[2][2];
#pragma unroll
    for (int ks = 0; ks < 2; ++ks)
#pragma unroll
      for (int ns = 0; ns < 2; ++ns) {
        const int brow = w * 32 + ns * 16 + lr;
        bb[ks][ns] = *(const bfrag*)(postl + brow * 128 + (((ks * 4 + lg) ^ (brow & 7)) << 4));
      }
    ffrag la[2][2] = {};
#pragma unroll
    for (int ks = 0; ks < 2; ++ks)
#pragma unroll
      for (int ts = 0; ts < 2; ++ts)
#pragma unroll
        for (int ns = 0; ns < 2; ++ns)
          la[ts][ns] = MFMA(cfU[ts * 2 + ks], bb[ks][ns], la[ts][ns]);
#pragma unroll
    for (int ts = 0; ts < 2; ++ts)
#pragma unroll
      for (int ns = 0; ns < 2; ++ns) {
        const int res = w * 32 + ns * 16 + lr;
        uint2 pkv;
        pkv.x = pack2(ftanh(la[ts][ns][0]), ftanh(la[ts][ns][1]));
        pkv.y = pack2(ftanh(la[ts][ns][2]), ftanh(la[ts][ns][3]));
        *(uint2*)(ll0 + (ts * 2 + (lg >> 1)) * 2048 + res * 16 + (lg & 1) * 8) = pkv;
      }
  }
  // reload cfU <- chunk 1 (consumed by L(1) in iter 0)
#pragma unroll
  for (int ts = 0; ts < 2; ++ts)
#pragma unroll
    for (int ks = 0; ks < 2; ++ks)
      cfU[ts * 2 + ks] = *(const bfrag*)(cbase + 4096 + ts * 2048 + ks * 64);
  __syncthreads();   // ll0 ready

  ffrag acc[2][8] = {};   // [ksub][ressub]: k in [32w,32w+32), res all 128
  char* llc = ll0;        // holds L(tc)
  char* lln = ll1;

#pragma unroll 2
  for (int tc = 0; tc < 32; ++tc) {
    // ---- L(tc+1): 8 MFMA from cfU + postl, tanh, store to lln ----
    if (tc < 31) {
      bfrag bb[2][2];
#pragma unroll
      for (int ks = 0; ks < 2; ++ks)
#pragma unroll
        for (int ns = 0; ns < 2; ++ns) {
          const int brow = w * 32 + ns * 16 + lr;
          bb[ks][ns] = *(const bfrag*)(postl + brow * 128 + (((ks * 4 + lg) ^ (brow & 7)) << 4));
        }
      ffrag la[2][2] = {};
#pragma unroll
      for (int ks = 0; ks < 2; ++ks)
#pragma unroll
        for (int ts = 0; ts < 2; ++ts)
#pragma unroll
          for (int ns = 0; ns < 2; ++ns)
            la[ts][ns] = MFMA(cfU[ts * 2 + ks], bb[ks][ns], la[ts][ns]);
#pragma unroll
      for (int ts = 0; ts < 2; ++ts)
#pragma unroll
        for (int ns = 0; ns < 2; ++ns) {
          const int res = w * 32 + ns * 16 + lr;
          uint2 pkv;
          pkv.x = pack2(ftanh(la[ts][ns][0]), ftanh(la[ts][ns][1]));
          pkv.y = pack2(ftanh(la[ts][ns][2]), ftanh(la[ts][ns][3]));
          *(uint2*)(lln + (ts * 2 + (lg >> 1)) * 2048 + res * 16 + (lg & 1) * 8) = pkv;
        }
    }

    // ---- issue next A-frag loads (cfU dead now -> regs recycle) ----
    {
      const int tc2 = (tc + 2 <= 31) ? tc + 2 : 31;   // clamp: redundant, in-bounds
      const int tk  = (tc + 1 <= 31) ? tc + 1 : 31;
      const char* c2 = cbase + (size_t)tc2 * 4096;
#pragma unroll
      for (int ts = 0; ts < 2; ++ts)
#pragma unroll
        for (int ks = 0; ks < 2; ++ks)
          cfU[ts * 2 + ks] = *(const bfrag*)(c2 + ts * 2048 + ks * 64);
      const char* k2 = kbase + (size_t)tk * 64;
      bfrag nk0 = *(const bfrag*)(k2);
      bfrag nk1 = *(const bfrag*)(k2 + 32768);

      // ---- GEMM(tc): acc += coeff(tc) x L(tc), K=32, from llc ----
#pragma unroll
      for (int ns = 0; ns < 8; ++ns) {
        bfrag bbr = *(const bfrag*)(llc + lg * 2048 + (ns * 16 + lr) * 16);
        acc[0][ns] = MFMA(kfU[0], bbr, acc[0][ns]);
        acc[1][ns] = MFMA(kfU[1], bbr, acc[1][ns]);
      }
      kfU[0] = nk0;
      kfU[1] = nk1;
    }

    { char* t = llc; llc = lln; lln = t; }
    __syncthreads();
  }

  // ---- epilogue: z[res] = sum_k wh[k] * tanh(acc + addterm) ----
  float zpart[8] = {0, 0, 0, 0, 0, 0, 0, 0};
#pragma unroll
  for (int ksb = 0; ksb < 2; ++ksb)
#pragma unroll
    for (int j = 0; j < 4; ++j) {
      const int k = w * 32 + ksb * 16 + lg * 4 + j;
      const float whk = wh[k];
      const unsigned short* arow = addterm + ((size_t)(b * 128 + k)) * 1024 + s0;
#pragma unroll
      for (int ns = 0; ns < 8; ++ns) {
        const int res = ns * 16 + lr;
        float h = ftanh(acc[ksb][ns][j] + b2f(arow[res]));
        zpart[ns] += whk * h;
      }
    }
#pragma unroll
  for (int ns = 0; ns < 8; ++ns) {
    zpart[ns] += __shfl_xor(zpart[ns], 16);
    zpart[ns] += __shfl_xor(zpart[ns], 32);
  }
  if (lg == 0) {
#pragma unroll
    for (int ns = 0; ns < 8; ++ns) zacc[w * 128 + ns * 16 + lr] = zpart[ns];
  }
  __syncthreads();
  if (tid < 128)
    zout[(size_t)b * 1024 + s0 + tid] =
        zacc[tid] + zacc[128 + tid] + zacc[256 + tid] + zacc[384 + tid];
}

// ---------------------------------------------------------------------------
// final: block (b, side), 1024 threads: softmax(z) -> weighted seq sum -> out
// ---------------------------------------------------------------------------
__global__ __launch_bounds__(1024) void final_kernel(
    const float* __restrict__ review, const float* __restrict__ post,
    const float* __restrict__ zp, const float* __restrict__ zr,
    float* __restrict__ out)
{
  const int b = blockIdx.x, side = blockIdx.y, tid = threadIdx.x;
  const int wid = tid >> 6, lane = tid & 63;
  __shared__ float zl[1024];
  __shared__ float red[16];
  __shared__ float cacc[16][64];

  const float* z = (side == 0) ? zp : zr;
  const float* seq = (side == 0) ? post : review;

  float v = z[(size_t)b * 1024 + tid];
  zl[tid] = v;
  float m = v;
#pragma unroll
  for (int off = 32; off; off >>= 1) m = fmaxf(m, __shfl_xor(m, off));
  if (lane == 0) red[wid] = m;
  __syncthreads();
  m = red[0];
#pragma unroll
  for (int i = 1; i < 16; ++i) m = fmaxf(m, red[i]);
  __syncthreads();

  float e = __expf(v - m);
  zl[tid] = e;
  float sm = e;
#pragma unroll
  for (int off = 32; off; off >>= 1) sm += __shfl_xor(sm, off);
  if (lane == 0) red[wid] = sm;
  __syncthreads();
  sm = red[0];
#pragma unroll
  for (int i = 1; i < 16; ++i) sm += red[i];
  const float inv = 1.0f / sm;

  const int d = lane;
  float a = 0.f;
  for (int n = wid * 64; n < wid * 64 + 64; ++n)
    a += zl[n] * seq[((size_t)(b * 1024 + n)) * 64 + d];
  cacc[wid][d] = a;
  __syncthreads();
  if (tid < 64) {
    float s = 0.f;
#pragma unroll
    for (int g = 0; g < 16; ++g) s += cacc[g][tid];
    out[b * 128 + side * 64 + tid] = s * inv;
  }
}

// ---------------------------------------------------------------------------
extern "C" void kernel_launch(void* const* d_in, const int* in_sizes, int n_in,
                              void* d_out, int out_size, void* d_ws, size_t ws_size,
                              hipStream_t stream) {
  const float* review = (const float*)d_in[0];
  const float* post   = (const float*)d_in[1];
  const float* Wl     = (const float*)d_in[2];
  const float* Wr     = (const float*)d_in[3];
  const float* Wp     = (const float*)d_in[4];
  const float* whr    = (const float*)d_in[5];
  const float* whp    = (const float*)d_in[6];
  float* out = (float*)d_out;

  char* ws = (char*)d_ws;
  unsigned short* RWb   = (unsigned short*)(ws);                        //  8 MiB
  unsigned short* Rb    = (unsigned short*)(ws + (size_t)8  * 1048576); // 16 MiB
  unsigned short* Pb    = (unsigned short*)(ws + (size_t)24 * 1048576); // 16 MiB
  unsigned short* postb = (unsigned short*)(ws + (size_t)40 * 1048576); //  8 MiB
  float* zp = (float*)(ws + (size_t)48 * 1048576);                      // 256 KiB
  float* zr = (float*)(ws + (size_t)48 * 1048576 + 262144);             // 256 KiB

  prep_kernel<<<dim3(8, 64, 2), dim3(256), 0, stream>>>(
      review, post, Wl, Wr, Wp, RWb, Rb, Pb, postb);
  hz_kernel<<<dim3(1024), dim3(256), 0, stream>>>(
      RWb, Rb, Pb, postb, whp, whr, zp, zr);
  final_kernel<<<dim3(64, 2), dim3(1024), 0, stream>>>(
      review, post, zp, zr, out);
}

// Round 5
// 121.139 us; speedup vs baseline: 1.1459x; 1.1459x over previous
//
#include <hip/hip_runtime.h>
#include <hip/hip_bf16.h>

// Problem constants: B=64, T=N=1024, d=64, k=128.

typedef __attribute__((ext_vector_type(8))) short bfrag;   // 8 x bf16 (4 VGPRs)
typedef __attribute__((ext_vector_type(4))) float ffrag;   // 4 x f32 acc

__device__ __forceinline__ unsigned short f2b(float f) {
  unsigned u = __builtin_bit_cast(unsigned, f);
  u += 0x7FFFu + ((u >> 16) & 1u);          // RNE f32 -> bf16 (finite inputs)
  return (unsigned short)(u >> 16);
}
__device__ __forceinline__ float b2f(unsigned short h) {
  return __builtin_bit_cast(float, (unsigned)h << 16);
}
__device__ __forceinline__ float ftanh(float x) {
  // tanh(x) = 1 - 2/(2^(x*2*log2e)+1); ~1e-6 abs err
  float e = __builtin_amdgcn_exp2f(x * 2.88539008177792681f);
  return fmaf(-2.0f, __builtin_amdgcn_rcpf(e + 1.0f), 1.0f);
}
// pack two f32 -> packed bf16 pair {lo, hi}; round-half-up (+0x8000) then one
// v_perm_b32 takes the two high halves.
__device__ __forceinline__ unsigned pack2(float lo, float hi) {
  unsigned a = __builtin_bit_cast(unsigned, lo) + 0x8000u;
  unsigned b = __builtin_bit_cast(unsigned, hi) + 0x8000u;
  return __builtin_amdgcn_perm(b, a, 0x07060302u);
}

#define MFMA(a, b, c) __builtin_amdgcn_mfma_f32_16x16x32_bf16((a), (b), (c), 0, 0, 0)

// ---------------------------------------------------------------------------
// prep: RWb = bf16(review@Wl)  [B,T,64]
//       Rb  = bf16(Wr@review^T) stored [B,128,T]
//       Pb  = bf16(Wp@post^T)   stored [B,128,N]
//       postb = bf16(post)      [B,N,64]
// ---------------------------------------------------------------------------
__global__ __launch_bounds__(256) void prep_kernel(
    const float* __restrict__ review, const float* __restrict__ post,
    const float* __restrict__ Wl, const float* __restrict__ Wr,
    const float* __restrict__ Wp,
    unsigned short* __restrict__ RWb, unsigned short* __restrict__ Rb,
    unsigned short* __restrict__ Pb, unsigned short* __restrict__ postb)
{
  const int chunk = blockIdx.x, b = blockIdx.y, side = blockIdx.z;
  const int tid = threadIdx.x, lane = tid & 63, w = tid >> 6;
  const int lr = lane & 15, lg = lane >> 4;
  const int r0 = chunk * 128;

  __shared__ __align__(16) unsigned short seqs[128][72];  // seq rows [r][d]
  __shared__ __align__(16) unsigned short wgt[128][72];   // Wr or Wp [k][d]
  __shared__ __align__(16) unsigned short wlt[64][72];    // Wl^T [i][d]

  const float* seq = (side == 0) ? review : post;
  // float4-vectorized: 8 x float4 per thread
#pragma unroll
  for (int jj = 0; jj < 8; ++jj) {
    int e = tid + jj * 256;            // e in [0,2048): r = e>>4, d4 = (e&15)*4
    int r = e >> 4, d4 = (e & 15) * 4;
    float4 v = *(const float4*)(seq + ((size_t)(b * 1024 + r0 + r)) * 64 + d4);
    unsigned lo = ((unsigned)f2b(v.y) << 16) | f2b(v.x);
    unsigned hi = ((unsigned)f2b(v.w) << 16) | f2b(v.z);
    *(uint2*)&seqs[r][d4] = make_uint2(lo, hi);
    if (side == 1)
      *(uint2*)(postb + ((size_t)(b * 1024 + r0 + r)) * 64 + d4) = make_uint2(lo, hi);
  }
  const float* wkd = (side == 0) ? Wr : Wp;
#pragma unroll
  for (int jj = 0; jj < 8; ++jj) {
    int e = tid + jj * 256;
    int k = e >> 4, d4 = (e & 15) * 4;
    float4 v = *(const float4*)(wkd + k * 64 + d4);
    unsigned lo = ((unsigned)f2b(v.y) << 16) | f2b(v.x);
    unsigned hi = ((unsigned)f2b(v.w) << 16) | f2b(v.z);
    *(uint2*)&wgt[k][d4] = make_uint2(lo, hi);
  }
  if (side == 0) {
    for (int i = tid; i < 64 * 64; i += 256) {
      int d = i >> 6, c = i & 63;
      wlt[c][d] = f2b(Wl[d * 64 + c]);
    }
  }
  __syncthreads();

  if (side == 0) {
    // RW = seqs @ Wl : [128 x 64]; wave w owns t in [32w, 32w+32)
    ffrag acc[2][4] = {};
#pragma unroll
    for (int ks = 0; ks < 2; ++ks)
#pragma unroll
      for (int ts = 0; ts < 2; ++ts) {
        bfrag a = *(const bfrag*)&seqs[w * 32 + ts * 16 + lr][ks * 32 + lg * 8];
#pragma unroll
        for (int is = 0; is < 4; ++is) {
          bfrag bb = *(const bfrag*)&wlt[is * 16 + lr][ks * 32 + lg * 8];
          acc[ts][is] = MFMA(a, bb, acc[ts][is]);
        }
      }
#pragma unroll
    for (int ts = 0; ts < 2; ++ts)
#pragma unroll
      for (int is = 0; is < 4; ++is)
#pragma unroll
        for (int j = 0; j < 4; ++j) {
          int t = r0 + w * 32 + ts * 16 + lg * 4 + j;
          int i2 = is * 16 + lr;
          RWb[((size_t)(b * 1024 + t)) * 64 + i2] = f2b(acc[ts][is][j]);
        }
  }
  {
    // R/P = wgt @ seqs^T : [128 k x 128 r]; wave w owns k in [32w, 32w+32)
    ffrag acc[2][8] = {};
#pragma unroll
    for (int ks = 0; ks < 2; ++ks)
#pragma unroll
      for (int ksb = 0; ksb < 2; ++ksb) {
        bfrag a = *(const bfrag*)&wgt[w * 32 + ksb * 16 + lr][ks * 32 + lg * 8];
#pragma unroll
        for (int ts = 0; ts < 8; ++ts) {
          bfrag bb = *(const bfrag*)&seqs[ts * 16 + lr][ks * 32 + lg * 8];
          acc[ksb][ts] = MFMA(a, bb, acc[ksb][ts]);
        }
      }
    unsigned short* dst = (side == 0) ? Rb : Pb;
#pragma unroll
    for (int ksb = 0; ksb < 2; ++ksb)
#pragma unroll
      for (int ts = 0; ts < 8; ++ts)
#pragma unroll
        for (int j = 0; j < 4; ++j) {
          int k = w * 32 + ksb * 16 + lg * 4 + j;
          int t = r0 + ts * 16 + lr;
          dst[((size_t)(b * 128 + k)) * 1024 + t] = f2b(acc[ksb][ts][j]);
        }
  }
}

// ---------------------------------------------------------------------------
// hz (fused hp+hr), v5: skewed software pipeline, ONE barrier per iteration.
//   role 0: z_p (resident=post strip, chunk over t, coeff=R, add=P)
//   role 1: z_r (resident=RW strip, chunk over n, coeff=P, add=R)
// Resident B-fragments are loop-invariant -> held in 16 VGPRs (bb), no postl.
// All global prefetches land in LDS stores (never feed MFMA directly).
// Iter tc: L(tc+1) from rwc -> lln  ||  GEMM(tc) from rlc+llc -> acc;
//          store prefetched chunk(tc+2)->rwn, coeff(tc+1)->rln; ONE barrier.
// LDS (40960 B, 4 blocks/CU):
//   rw0/rw1 @0/@4096: [32 rows][128B] XOR-swizzled chunk
//   rl0/rl1 @8192/@16384: [4 slots][128 k][16B] frag-major coeff
//   ll0/ll1 @24576/@32768: [4 slots][128 res][16B] frag-major L (zacc alias)
// ---------------------------------------------------------------------------
__global__ __launch_bounds__(256, 4) void hz_kernel(
    const unsigned short* __restrict__ RWb, const unsigned short* __restrict__ Rb,
    const unsigned short* __restrict__ Pb, const unsigned short* __restrict__ postb,
    const float* __restrict__ whp, const float* __restrict__ whr,
    float* __restrict__ zp, float* __restrict__ zr)
{
  const int orig = blockIdx.x;
  const int swz = (orig & 7) * 128 + (orig >> 3);   // XCD-chunked, bijective
  const int strip = swz & 7, pair = swz >> 3;
  const int b = pair & 63, role = pair >> 6;
  const int s0 = strip * 128;
  const int tid = threadIdx.x, lane = tid & 63, w = tid >> 6;
  const int lr = lane & 15, lg = lane >> 4;

  const unsigned short* resident = role ? RWb : postb;
  const unsigned short* chunkseq = role ? postb : RWb;
  const unsigned short* coeff    = role ? Pb : Rb;
  const unsigned short* addterm  = role ? Rb : Pb;
  const float* wh                = role ? whr : whp;
  float* zout                    = role ? zr : zp;

  __shared__ __align__(16) char smem[40960];
  char* rw0 = smem;
  char* rw1 = smem + 4096;
  char* rl0 = smem + 8192;
  char* rl1 = smem + 16384;
  char* ll0 = smem + 24576;
  char* ll1 = smem + 32768;
  float* zacc = (float*)(smem + 24576);  // alias ll0 (post-loop only)

  // per-lane global bases
  const char* cbase = (const char*)chunkseq + (size_t)b * 131072;       // rows of 128B
  const char* kbase = (const char*)coeff + (size_t)b * 262144;          // rows of 2048B
  const int pr = tid >> 3, pslot = tid & 7;       // chunk staging mapping
  const int pk = tid >> 2, ppart = tid & 3;       // coeff staging mapping

  // ---- loop-invariant resident B-frags (16 VGPRs) ----
  bfrag bb[2][2];
  {
    const char* rbase = (const char*)resident + ((size_t)(b * 1024 + s0)) * 128;
#pragma unroll
    for (int ks = 0; ks < 2; ++ks)
#pragma unroll
      for (int ns = 0; ns < 2; ++ns)
        bb[ks][ns] = *(const bfrag*)(rbase + (w * 32 + ns * 16 + lr) * 128 + ks * 64 + lg * 16);
  }

  // ---- prologue: chunk(0) -> rw0, coeff(0) -> rl0 ----
  {
    uint4 c0 = *(const uint4*)(cbase + pr * 128 + pslot * 16);
    uint4 k0a = *(const uint4*)(kbase + (size_t)pk * 2048 + ppart * 16);
    uint4 k0b = *(const uint4*)(kbase + (size_t)(pk + 64) * 2048 + ppart * 16);
    *(uint4*)(rw0 + pr * 128 + ((pslot ^ (pr & 7)) << 4)) = c0;
    *(uint4*)(rl0 + ppart * 2048 + pk * 16) = k0a;
    *(uint4*)(rl0 + ppart * 2048 + (pk + 64) * 16) = k0b;
  }
  __syncthreads();   // rw0, rl0 ready

  // ---- prologue: L(0) -> ll0; stage chunk(1) -> rw1 ----
  {
    uint4 c1 = *(const uint4*)(cbase + 4096 + pr * 128 + pslot * 16);
    ffrag la[2][2] = {};
#pragma unroll
    for (int ks = 0; ks < 2; ++ks)
#pragma unroll
      for (int ts = 0; ts < 2; ++ts) {
        const int arow = ts * 16 + lr;
        bfrag a = *(const bfrag*)(rw0 + arow * 128 + (((ks * 4 + lg) ^ (arow & 7)) << 4));
#pragma unroll
        for (int ns = 0; ns < 2; ++ns)
          la[ts][ns] = MFMA(a, bb[ks][ns], la[ts][ns]);
      }
#pragma unroll
    for (int ts = 0; ts < 2; ++ts)
#pragma unroll
      for (int ns = 0; ns < 2; ++ns) {
        const int res = w * 32 + ns * 16 + lr;
        uint2 pkv;
        pkv.x = pack2(ftanh(la[ts][ns][0]), ftanh(la[ts][ns][1]));
        pkv.y = pack2(ftanh(la[ts][ns][2]), ftanh(la[ts][ns][3]));
        *(uint2*)(ll0 + (ts * 2 + (lg >> 1)) * 2048 + res * 16 + (lg & 1) * 8) = pkv;
      }
    *(uint4*)(rw1 + pr * 128 + ((pslot ^ (pr & 7)) << 4)) = c1;
  }
  __syncthreads();   // ll0 = L(0), rw1 = chunk(1)

  ffrag acc[2][8] = {};   // [ksub][ressub]: k in [32w,32w+32), res all 128
  char* rwc = rw1; char* rwn = rw0;   // rwc holds chunk(tc+1)
  char* rlc = rl0; char* rln = rl1;   // rlc holds coeff(tc)
  char* llc = ll0; char* lln = ll1;   // llc holds L(tc)

#pragma unroll 2
  for (int tc = 0; tc < 32; ++tc) {
    // ---- issue global prefetches (consumed by LDS stores at iter bottom) ----
    uint4 pf_c, pf_k0, pf_k1;
    if (tc < 30)
      pf_c = *(const uint4*)(cbase + (size_t)(tc + 2) * 4096 + pr * 128 + pslot * 16);
    if (tc < 31) {
      const char* k2 = kbase + (size_t)(tc + 1) * 64;
      pf_k0 = *(const uint4*)(k2 + (size_t)pk * 2048 + ppart * 16);
      pf_k1 = *(const uint4*)(k2 + (size_t)(pk + 64) * 2048 + ppart * 16);
    }

    // ---- L(tc+1): rwc a-frags x bb -> tanh -> lln ----
    if (tc < 31) {
      ffrag la[2][2] = {};
#pragma unroll
      for (int ks = 0; ks < 2; ++ks)
#pragma unroll
        for (int ts = 0; ts < 2; ++ts) {
          const int arow = ts * 16 + lr;
          bfrag a = *(const bfrag*)(rwc + arow * 128 + (((ks * 4 + lg) ^ (arow & 7)) << 4));
#pragma unroll
          for (int ns = 0; ns < 2; ++ns)
            la[ts][ns] = MFMA(a, bb[ks][ns], la[ts][ns]);
        }
#pragma unroll
      for (int ts = 0; ts < 2; ++ts)
#pragma unroll
        for (int ns = 0; ns < 2; ++ns) {
          const int res = w * 32 + ns * 16 + lr;
          uint2 pkv;
          pkv.x = pack2(ftanh(la[ts][ns][0]), ftanh(la[ts][ns][1]));
          pkv.y = pack2(ftanh(la[ts][ns][2]), ftanh(la[ts][ns][3]));
          *(uint2*)(lln + (ts * 2 + (lg >> 1)) * 2048 + res * 16 + (lg & 1) * 8) = pkv;
        }
    }

    // ---- GEMM(tc): acc += coeff(tc) x L(tc)  (K=32, from rlc+llc) ----
    {
      bfrag a0 = *(const bfrag*)(rlc + lg * 2048 + (w * 32 + lr) * 16);
      bfrag a1 = *(const bfrag*)(rlc + lg * 2048 + (w * 32 + 16 + lr) * 16);
#pragma unroll
      for (int ns = 0; ns < 8; ++ns) {
        bfrag bbr = *(const bfrag*)(llc + lg * 2048 + (ns * 16 + lr) * 16);
        acc[0][ns] = MFMA(a0, bbr, acc[0][ns]);
        acc[1][ns] = MFMA(a1, bbr, acc[1][ns]);
      }
    }

    // ---- store prefetches into retired buffers ----
    if (tc < 30)
      *(uint4*)(rwn + pr * 128 + ((pslot ^ (pr & 7)) << 4)) = pf_c;
    if (tc < 31) {
      *(uint4*)(rln + ppart * 2048 + pk * 16) = pf_k0;
      *(uint4*)(rln + ppart * 2048 + (pk + 64) * 16) = pf_k1;
    }
    __syncthreads();   // ONE barrier: lln/rwn/rln now visible, llc/rlc retired

    { char* t = rwc; rwc = rwn; rwn = t; }
    { char* t = rlc; rlc = rln; rln = t; }
    { char* t = llc; llc = lln; lln = t; }
  }

  // ---- epilogue: z[res] = sum_k wh[k] * tanh(acc + addterm) ----
  float zpart[8] = {0, 0, 0, 0, 0, 0, 0, 0};
#pragma unroll
  for (int ksb = 0; ksb < 2; ++ksb)
#pragma unroll
    for (int j = 0; j < 4; ++j) {
      const int k = w * 32 + ksb * 16 + lg * 4 + j;
      const float whk = wh[k];
      const unsigned short* arow = addterm + ((size_t)(b * 128 + k)) * 1024 + s0;
#pragma unroll
      for (int ns = 0; ns < 8; ++ns) {
        const int res = ns * 16 + lr;
        float h = ftanh(acc[ksb][ns][j] + b2f(arow[res]));
        zpart[ns] += whk * h;
      }
    }
#pragma unroll
  for (int ns = 0; ns < 8; ++ns) {
    zpart[ns] += __shfl_xor(zpart[ns], 16);
    zpart[ns] += __shfl_xor(zpart[ns], 32);
  }
  if (lg == 0) {
#pragma unroll
    for (int ns = 0; ns < 8; ++ns) zacc[w * 128 + ns * 16 + lr] = zpart[ns];
  }
  __syncthreads();
  if (tid < 128)
    zout[(size_t)b * 1024 + s0 + tid] =
        zacc[tid] + zacc[128 + tid] + zacc[256 + tid] + zacc[384 + tid];
}

// ---------------------------------------------------------------------------
// final: block (b, side), 1024 threads: softmax(z) -> weighted seq sum -> out
// ---------------------------------------------------------------------------
__global__ __launch_bounds__(1024) void final_kernel(
    const float* __restrict__ review, const float* __restrict__ post,
    const float* __restrict__ zp, const float* __restrict__ zr,
    float* __restrict__ out)
{
  const int b = blockIdx.x, side = blockIdx.y, tid = threadIdx.x;
  const int wid = tid >> 6, lane = tid & 63;
  __shared__ float zl[1024];
  __shared__ float red[16];
  __shared__ float cacc[16][64];

  const float* z = (side == 0) ? zp : zr;
  const float* seq = (side == 0) ? post : review;

  float v = z[(size_t)b * 1024 + tid];
  zl[tid] = v;
  float m = v;
#pragma unroll
  for (int off = 32; off; off >>= 1) m = fmaxf(m, __shfl_xor(m, off));
  if (lane == 0) red[wid] = m;
  __syncthreads();
  m = red[0];
#pragma unroll
  for (int i = 1; i < 16; ++i) m = fmaxf(m, red[i]);
  __syncthreads();

  float e = __expf(v - m);
  zl[tid] = e;
  float sm = e;
#pragma unroll
  for (int off = 32; off; off >>= 1) sm += __shfl_xor(sm, off);
  if (lane == 0) red[wid] = sm;
  __syncthreads();
  sm = red[0];
#pragma unroll
  for (int i = 1; i < 16; ++i) sm += red[i];
  const float inv = 1.0f / sm;

  const int d = lane;
  float a = 0.f;
  for (int n = wid * 64; n < wid * 64 + 64; ++n)
    a += zl[n] * seq[((size_t)(b * 1024 + n)) * 64 + d];
  cacc[wid][d] = a;
  __syncthreads();
  if (tid < 64) {
    float s = 0.f;
#pragma unroll
    for (int g = 0; g < 16; ++g) s += cacc[g][tid];
    out[b * 128 + side * 64 + tid] = s * inv;
  }
}

// ---------------------------------------------------------------------------
extern "C" void kernel_launch(void* const* d_in, const int* in_sizes, int n_in,
                              void* d_out, int out_size, void* d_ws, size_t ws_size,
                              hipStream_t stream) {
  const float* review = (const float*)d_in[0];
  const float* post   = (const float*)d_in[1];
  const float* Wl     = (const float*)d_in[2];
  const float* Wr     = (const float*)d_in[3];
  const float* Wp     = (const float*)d_in[4];
  const float* whr    = (const float*)d_in[5];
  const float* whp    = (const float*)d_in[6];
  float* out = (float*)d_out;

  char* ws = (char*)d_ws;
  unsigned short* RWb   = (unsigned short*)(ws);                        //  8 MiB
  unsigned short* Rb    = (unsigned short*)(ws + (size_t)8  * 1048576); // 16 MiB
  unsigned short* Pb    = (unsigned short*)(ws + (size_t)24 * 1048576); // 16 MiB
  unsigned short* postb = (unsigned short*)(ws + (size_t)40 * 1048576); //  8 MiB
  float* zp = (float*)(ws + (size_t)48 * 1048576);                      // 256 KiB
  float* zr = (float*)(ws + (size_t)48 * 1048576 + 262144);             // 256 KiB

  prep_kernel<<<dim3(8, 64, 2), dim3(256), 0, stream>>>(
      review, post, Wl, Wr, Wp, RWb, Rb, Pb, postb);
  hz_kernel<<<dim3(1024), dim3(256), 0, stream>>>(
      RWb, Rb, Pb, postb, whp, whr, zp, zr);
  final_kernel<<<dim3(64, 2), dim3(1024), 0, stream>>>(
      review, post, zp, zr, out);
}

// Round 6
// 103.739 us; speedup vs baseline: 1.3381x; 1.1677x over previous
//
#include <hip/hip_runtime.h>
#include <hip/hip_bf16.h>

// Problem constants: B=64, T=N=1024, d=64, k=128.

typedef __attribute__((ext_vector_type(8))) short bfrag;   // 8 x bf16 (4 VGPRs)
typedef __attribute__((ext_vector_type(4))) float ffrag;   // 4 x f32 acc

typedef const __attribute__((address_space(1))) unsigned GAS_U;
typedef __attribute__((address_space(3))) unsigned LAS_U;

__device__ __forceinline__ void gload16(const void* g, void* l) {
  // async global->LDS, 16B per lane; LDS dest = wave-uniform base + lane*16
  __builtin_amdgcn_global_load_lds((GAS_U*)g, (LAS_U*)l, 16, 0, 0);
}

__device__ __forceinline__ unsigned short f2b(float f) {
  unsigned u = __builtin_bit_cast(unsigned, f);
  u += 0x7FFFu + ((u >> 16) & 1u);          // RNE f32 -> bf16 (finite inputs)
  return (unsigned short)(u >> 16);
}
__device__ __forceinline__ float b2f(unsigned short h) {
  return __builtin_bit_cast(float, (unsigned)h << 16);
}
__device__ __forceinline__ float ftanh(float x) {
  // tanh(x) = 1 - 2/(2^(x*2*log2e)+1); ~1e-6 abs err
  float e = __builtin_amdgcn_exp2f(x * 2.88539008177792681f);
  return fmaf(-2.0f, __builtin_amdgcn_rcpf(e + 1.0f), 1.0f);
}
// packed bf16 pair {lo in low16, hi in high16}, RNE, single instruction
__device__ __forceinline__ unsigned cvtpk(float lo, float hi) {
  unsigned r;
  asm("v_cvt_pk_bf16_f32 %0, %1, %2" : "=v"(r) : "v"(lo), "v"(hi));
  return r;
}

#define MFMA(a, b, c) __builtin_amdgcn_mfma_f32_16x16x32_bf16((a), (b), (c), 0, 0, 0)

// ---------------------------------------------------------------------------
// prep: RWb = bf16(review@Wl)  [B,T,64]
//       Rb  = bf16(Wr@review^T) stored [B,128,T]
//       Pb  = bf16(Wp@post^T)   stored [B,128,N]
//       postb = bf16(post)      [B,N,64]
// ---------------------------------------------------------------------------
__global__ __launch_bounds__(256) void prep_kernel(
    const float* __restrict__ review, const float* __restrict__ post,
    const float* __restrict__ Wl, const float* __restrict__ Wr,
    const float* __restrict__ Wp,
    unsigned short* __restrict__ RWb, unsigned short* __restrict__ Rb,
    unsigned short* __restrict__ Pb, unsigned short* __restrict__ postb)
{
  const int chunk = blockIdx.x, b = blockIdx.y, side = blockIdx.z;
  const int tid = threadIdx.x, lane = tid & 63, w = tid >> 6;
  const int lr = lane & 15, lg = lane >> 4;
  const int r0 = chunk * 128;

  __shared__ __align__(16) unsigned short seqs[128][72];  // seq rows [r][d]
  __shared__ __align__(16) unsigned short wgt[128][72];   // Wr or Wp [k][d]
  __shared__ __align__(16) unsigned short wlt[64][72];    // Wl^T [i][d]

  const float* seq = (side == 0) ? review : post;
#pragma unroll
  for (int jj = 0; jj < 8; ++jj) {
    int e = tid + jj * 256;            // r = e>>4, d4 = (e&15)*4
    int r = e >> 4, d4 = (e & 15) * 4;
    float4 v = *(const float4*)(seq + ((size_t)(b * 1024 + r0 + r)) * 64 + d4);
    unsigned lo = ((unsigned)f2b(v.y) << 16) | f2b(v.x);
    unsigned hi = ((unsigned)f2b(v.w) << 16) | f2b(v.z);
    *(uint2*)&seqs[r][d4] = make_uint2(lo, hi);
    if (side == 1)
      *(uint2*)(postb + ((size_t)(b * 1024 + r0 + r)) * 64 + d4) = make_uint2(lo, hi);
  }
  const float* wkd = (side == 0) ? Wr : Wp;
#pragma unroll
  for (int jj = 0; jj < 8; ++jj) {
    int e = tid + jj * 256;
    int k = e >> 4, d4 = (e & 15) * 4;
    float4 v = *(const float4*)(wkd + k * 64 + d4);
    unsigned lo = ((unsigned)f2b(v.y) << 16) | f2b(v.x);
    unsigned hi = ((unsigned)f2b(v.w) << 16) | f2b(v.z);
    *(uint2*)&wgt[k][d4] = make_uint2(lo, hi);
  }
  if (side == 0) {
    for (int i = tid; i < 64 * 64; i += 256) {
      int d = i >> 6, c = i & 63;
      wlt[c][d] = f2b(Wl[d * 64 + c]);
    }
  }
  __syncthreads();

  if (side == 0) {
    // RW = seqs @ Wl : [128 x 64]; wave w owns t in [32w, 32w+32)
    ffrag acc[2][4] = {};
#pragma unroll
    for (int ks = 0; ks < 2; ++ks)
#pragma unroll
      for (int ts = 0; ts < 2; ++ts) {
        bfrag a = *(const bfrag*)&seqs[w * 32 + ts * 16 + lr][ks * 32 + lg * 8];
#pragma unroll
        for (int is = 0; is < 4; ++is) {
          bfrag bb = *(const bfrag*)&wlt[is * 16 + lr][ks * 32 + lg * 8];
          acc[ts][is] = MFMA(a, bb, acc[ts][is]);
        }
      }
#pragma unroll
    for (int ts = 0; ts < 2; ++ts)
#pragma unroll
      for (int is = 0; is < 4; ++is)
#pragma unroll
        for (int j = 0; j < 4; ++j) {
          int t = r0 + w * 32 + ts * 16 + lg * 4 + j;
          int i2 = is * 16 + lr;
          RWb[((size_t)(b * 1024 + t)) * 64 + i2] = f2b(acc[ts][is][j]);
        }
  }
  {
    // R/P = wgt @ seqs^T : [128 k x 128 r]; wave w owns k in [32w, 32w+32)
    ffrag acc[2][8] = {};
#pragma unroll
    for (int ks = 0; ks < 2; ++ks)
#pragma unroll
      for (int ksb = 0; ksb < 2; ++ksb) {
        bfrag a = *(const bfrag*)&wgt[w * 32 + ksb * 16 + lr][ks * 32 + lg * 8];
#pragma unroll
        for (int ts = 0; ts < 8; ++ts) {
          bfrag bb = *(const bfrag*)&seqs[ts * 16 + lr][ks * 32 + lg * 8];
          acc[ksb][ts] = MFMA(a, bb, acc[ksb][ts]);
        }
      }
    unsigned short* dst = (side == 0) ? Rb : Pb;
#pragma unroll
    for (int ksb = 0; ksb < 2; ++ksb)
#pragma unroll
      for (int ts = 0; ts < 8; ++ts)
#pragma unroll
        for (int j = 0; j < 4; ++j) {
          int k = w * 32 + ksb * 16 + lg * 4 + j;
          int t = r0 + ts * 16 + lr;
          dst[((size_t)(b * 128 + k)) * 1024 + t] = f2b(acc[ksb][ts][j]);
        }
  }
}

// ---------------------------------------------------------------------------
// hz (fused hp+hr), v6: r3 skeleton (2 barriers/iter) + global_load_lds
// staging (no staging VGPRs, no store phase) + resident B-frags in registers
// + v_cvt_pk_bf16_f32 pack.
//   role 0: z_p (resident=post strip, chunk over t, coeff=R, add=P)
//   role 1: z_r (resident=RW strip, chunk over n, coeff=P, add=R)
// LDS (32768 B, 4 blocks/CU):
//   rw0/rw1 @0/@4096:     [32 rows][128B] chunk; XOR-swizzle via PRE-SWIZZLED
//                          global source (dest linear for gload16)
//   rl0/rl1 @8192/@16384: [4 part][128 k][16B] frag-major coeff (dest linear)
//   ll @24576:            [4 slot][128 res][16B] frag-major L (zacc alias)
// Iter tc: issue gload16 x3 for (tc+1) into buf^1; L-phase(tc) from rw[cur]
// x bb-regs -> tanh -> ll; B2 (drains gloads, covered by compute); GEMM(tc)
// from rl[cur]+ll -> acc; B3.
// ---------------------------------------------------------------------------
__global__ __launch_bounds__(256, 4) void hz_kernel(
    const unsigned short* __restrict__ RWb, const unsigned short* __restrict__ Rb,
    const unsigned short* __restrict__ Pb, const unsigned short* __restrict__ postb,
    const float* __restrict__ whp, const float* __restrict__ whr,
    float* __restrict__ zp, float* __restrict__ zr)
{
  const int orig = blockIdx.x;
  const int swz = (orig & 7) * 128 + (orig >> 3);   // XCD-chunked, bijective
  const int strip = swz & 7, pair = swz >> 3;
  const int b = pair & 63, role = pair >> 6;
  const int s0 = strip * 128;
  const int tid = threadIdx.x, lane = tid & 63, w = tid >> 6;
  const int lr = lane & 15, lg = lane >> 4;

  const unsigned short* resident = role ? RWb : postb;
  const unsigned short* chunkseq = role ? postb : RWb;
  const unsigned short* coeff    = role ? Pb : Rb;
  const unsigned short* addterm  = role ? Rb : Pb;
  const float* wh                = role ? whr : whp;
  float* zout                    = role ? zr : zp;

  __shared__ __align__(16) char smem[32768];
  float* zacc = (float*)(smem + 24576);  // alias ll (post-loop only)

  // ---- per-lane pre-swizzled global sources (dest stays linear) ----
  // chunk: dest flat = w*1024 + lane*16 -> row = w*8 + (lane>>3), slot = lane&7
  const int crow = (w << 3) + (lane >> 3), cslot = lane & 7;
  const char* csrc = (const char*)chunkseq + (size_t)b * 131072
                     + crow * 128 + ((cslot ^ (crow & 7)) << 4);   // + tc*4096
  // coeff: dest flat = q*4096 + w*1024 + lane*16 -> part = q*2+(w>>1),
  //        kk = (w&1)*64 + lane; src = kk*2048 + part*16 (+ tc*64, q:+32B)
  const int kk = ((w & 1) << 6) + lane;
  const char* ksrc = (const char*)coeff + (size_t)b * 262144
                     + (size_t)kk * 2048 + (w >> 1) * 16;          // + tc*64
  // LDS dest wave bases (wave-uniform)
  const int woff = w << 10;

  // ---- loop-invariant resident B-frags (16 VGPRs) ----
  bfrag bb[2][2];
  {
    const char* rbase = (const char*)resident + ((size_t)(b * 1024 + s0)) * 128;
#pragma unroll
    for (int ks = 0; ks < 2; ++ks)
#pragma unroll
      for (int ns = 0; ns < 2; ++ns)
        bb[ks][ns] = *(const bfrag*)(rbase + (w * 32 + ns * 16 + lr) * 128 + ks * 64 + lg * 16);
  }

  // ---- prologue: stage chunk(0) -> rw0, coeff(0) -> rl0 ----
  gload16(csrc, smem + woff);
  gload16(ksrc, smem + 8192 + woff);
  gload16(ksrc + 32, smem + 12288 + woff);
  __syncthreads();

  ffrag acc[2][8] = {};   // [ksub][ressub]: k in [32w,32w+32), res all 128
  int cur = 0;

#pragma unroll 2
  for (int tc = 0; tc < 32; ++tc) {
    // ---- issue async staging for next chunk into buf cur^1 ----
    if (tc < 31) {
      const int nb = cur ^ 1;
      const char* cs = csrc + (size_t)(tc + 1) * 4096;
      const char* ks2 = ksrc + (tc + 1) * 64;
      gload16(cs, smem + nb * 4096 + woff);
      gload16(ks2, smem + 8192 + nb * 8192 + woff);
      gload16(ks2 + 32, smem + 8192 + nb * 8192 + 4096 + woff);
    }

    // ---- L-phase(tc): a-frags from rw[cur], B from bb regs ----
    {
      const char* rwc = smem + cur * 4096;
#pragma unroll
      for (int ts = 0; ts < 2; ++ts) {
        ffrag la[2] = {};
#pragma unroll
        for (int ks = 0; ks < 2; ++ks) {
          const int arow = ts * 16 + lr;
          bfrag a = *(const bfrag*)(rwc + arow * 128 + (((ks * 4 + lg) ^ (arow & 7)) << 4));
#pragma unroll
          for (int ns = 0; ns < 2; ++ns)
            la[ns] = MFMA(a, bb[ks][ns], la[ns]);
        }
#pragma unroll
        for (int ns = 0; ns < 2; ++ns) {
          const int res = w * 32 + ns * 16 + lr;
          uint2 pkv;
          pkv.x = cvtpk(ftanh(la[ns][0]), ftanh(la[ns][1]));
          pkv.y = cvtpk(ftanh(la[ns][2]), ftanh(la[ns][3]));
          *(uint2*)(smem + 24576 + (ts * 2 + (lg >> 1)) * 2048 + res * 16 + (lg & 1) * 8) = pkv;
        }
      }
    }
    __syncthreads();   // B2: ll visible; staging gloads drained (covered)

    // ---- GEMM(tc): acc += coeff(tc) x L(tc), K=32 ----
    {
      const char* rlc = smem + 8192 + cur * 8192;
      bfrag a0 = *(const bfrag*)(rlc + lg * 2048 + (w * 32 + lr) * 16);
      bfrag a1 = *(const bfrag*)(rlc + lg * 2048 + (w * 32 + 16 + lr) * 16);
#pragma unroll
      for (int ns = 0; ns < 8; ++ns) {
        bfrag bbr = *(const bfrag*)(smem + 24576 + lg * 2048 + (ns * 16 + lr) * 16);
        acc[0][ns] = MFMA(a0, bbr, acc[0][ns]);
        acc[1][ns] = MFMA(a1, bbr, acc[1][ns]);
      }
    }
    __syncthreads();   // B3: ll/rl[cur] reads retired
    cur ^= 1;
  }

  // ---- epilogue: z[res] = sum_k wh[k] * tanh(acc + addterm) ----
  float zpart[8] = {0, 0, 0, 0, 0, 0, 0, 0};
#pragma unroll
  for (int ksb = 0; ksb < 2; ++ksb)
#pragma unroll
    for (int j = 0; j < 4; ++j) {
      const int k = w * 32 + ksb * 16 + lg * 4 + j;
      const float whk = wh[k];
      const unsigned short* arow = addterm + ((size_t)(b * 128 + k)) * 1024 + s0;
#pragma unroll
      for (int ns = 0; ns < 8; ++ns) {
        const int res = ns * 16 + lr;
        float h = ftanh(acc[ksb][ns][j] + b2f(arow[res]));
        zpart[ns] += whk * h;
      }
    }
#pragma unroll
  for (int ns = 0; ns < 8; ++ns) {
    zpart[ns] += __shfl_xor(zpart[ns], 16);
    zpart[ns] += __shfl_xor(zpart[ns], 32);
  }
  if (lg == 0) {
#pragma unroll
    for (int ns = 0; ns < 8; ++ns) zacc[w * 128 + ns * 16 + lr] = zpart[ns];
  }
  __syncthreads();
  if (tid < 128)
    zout[(size_t)b * 1024 + s0 + tid] =
        zacc[tid] + zacc[128 + tid] + zacc[256 + tid] + zacc[384 + tid];
}

// ---------------------------------------------------------------------------
// final: block (b, side), 1024 threads: softmax(z) -> weighted seq sum -> out
// ---------------------------------------------------------------------------
__global__ __launch_bounds__(1024) void final_kernel(
    const float* __restrict__ review, const float* __restrict__ post,
    const float* __restrict__ zp, const float* __restrict__ zr,
    float* __restrict__ out)
{
  const int b = blockIdx.x, side = blockIdx.y, tid = threadIdx.x;
  const int wid = tid >> 6, lane = tid & 63;
  __shared__ float zl[1024];
  __shared__ float red[16];
  __shared__ float cacc[16][64];

  const float* z = (side == 0) ? zp : zr;
  const float* seq = (side == 0) ? post : review;

  float v = z[(size_t)b * 1024 + tid];
  zl[tid] = v;
  float m = v;
#pragma unroll
  for (int off = 32; off; off >>= 1) m = fmaxf(m, __shfl_xor(m, off));
  if (lane == 0) red[wid] = m;
  __syncthreads();
  m = red[0];
#pragma unroll
  for (int i = 1; i < 16; ++i) m = fmaxf(m, red[i]);
  __syncthreads();

  float e = __expf(v - m);
  zl[tid] = e;
  float sm = e;
#pragma unroll
  for (int off = 32; off; off >>= 1) sm += __shfl_xor(sm, off);
  if (lane == 0) red[wid] = sm;
  __syncthreads();
  sm = red[0];
#pragma unroll
  for (int i = 1; i < 16; ++i) sm += red[i];
  const float inv = 1.0f / sm;

  const int d = lane;
  float a = 0.f;
  for (int n = wid * 64; n < wid * 64 + 64; ++n)
    a += zl[n] * seq[((size_t)(b * 1024 + n)) * 64 + d];
  cacc[wid][d] = a;
  __syncthreads();
  if (tid < 64) {
    float s = 0.f;
#pragma unroll
    for (int g = 0; g < 16; ++g) s += cacc[g][tid];
    out[b * 128 + side * 64 + tid] = s * inv;
  }
}

// ---------------------------------------------------------------------------
extern "C" void kernel_launch(void* const* d_in, const int* in_sizes, int n_in,
                              void* d_out, int out_size, void* d_ws, size_t ws_size,
                              hipStream_t stream) {
  const float* review = (const float*)d_in[0];
  const float* post   = (const float*)d_in[1];
  const float* Wl     = (const float*)d_in[2];
  const float* Wr     = (const float*)d_in[3];
  const float* Wp     = (const float*)d_in[4];
  const float* whr    = (const float*)d_in[5];
  const float* whp    = (const float*)d_in[6];
  float* out = (float*)d_out;

  char* ws = (char*)d_ws;
  unsigned short* RWb   = (unsigned short*)(ws);                        //  8 MiB
  unsigned short* Rb    = (unsigned short*)(ws + (size_t)8  * 1048576); // 16 MiB
  unsigned short* Pb    = (unsigned short*)(ws + (size_t)24 * 1048576); // 16 MiB
  unsigned short* postb = (unsigned short*)(ws + (size_t)40 * 1048576); //  8 MiB
  float* zp = (float*)(ws + (size_t)48 * 1048576);                      // 256 KiB
  float* zr = (float*)(ws + (size_t)48 * 1048576 + 262144);             // 256 KiB

  prep_kernel<<<dim3(8, 64, 2), dim3(256), 0, stream>>>(
      review, post, Wl, Wr, Wp, RWb, Rb, Pb, postb);
  hz_kernel<<<dim3(1024), dim3(256), 0, stream>>>(
      RWb, Rb, Pb, postb, whp, whr, zp, zr);
  final_kernel<<<dim3(64, 2), dim3(1024), 0, stream>>>(
      review, post, zp, zr, out);
}